// Round 3
// baseline (429.988 us; speedup 1.0000x reference)
//
#include <hip/hip_runtime.h>
#include <cstdint>
#include <cstddef>

#define N_TOK 4096   // 2*2048 tokens
#define DM 1024      // d_model
#define FH 4096      // ffn hidden
#define NE 8         // experts

typedef __attribute__((ext_vector_type(8))) short short8;  // 8 bf16
typedef __attribute__((ext_vector_type(4))) float f32x4;

#define BAR() asm volatile("s_barrier" ::: "memory")
#define WAITV2() asm volatile("s_waitcnt vmcnt(2)" ::: "memory")

__device__ __forceinline__ unsigned short f2bf(float f) {
  unsigned u = __float_as_uint(f);
  u += 0x7fffu + ((u >> 16) & 1u);   // RNE
  return (unsigned short)(u >> 16);
}

// ---------------- fp32 -> bf16 conversion ----------------
__global__ void cvt_kernel(const float* __restrict__ src, unsigned short* __restrict__ dst, int n4) {
  int stride = gridDim.x * blockDim.x;
  for (int i = blockIdx.x * blockDim.x + threadIdx.x; i < n4; i += stride) {
    float4 v = reinterpret_cast<const float4*>(src)[i];
    ushort4 o;
    o.x = f2bf(v.x); o.y = f2bf(v.y); o.z = f2bf(v.z); o.w = f2bf(v.w);
    reinterpret_cast<ushort4*>(dst)[i] = o;
  }
}

// ---------------- router ----------------
__global__ void router_kernel(const float* __restrict__ x, const float* __restrict__ Wr,
                              float* __restrict__ partials, unsigned char* __restrict__ topidx,
                              float* __restrict__ pslot) {
  __shared__ float sp[NE];
  int lane = threadIdx.x & 63;
  int wv = threadIdx.x >> 6;
  int token = blockIdx.x * 4 + wv;
  if (threadIdx.x < NE) sp[threadIdx.x] = 0.f;
  __syncthreads();

  const float4* xr = (const float4*)(x + (size_t)token * DM);
  float acc[NE];
#pragma unroll
  for (int e = 0; e < NE; e++) acc[e] = 0.f;
#pragma unroll
  for (int d = lane; d < DM / 4; d += 64) {
    float4 xv = xr[d];
#pragma unroll
    for (int e = 0; e < NE; e++) {
      float4 wv4 = ((const float4*)(Wr + e * DM))[d];
      acc[e] += xv.x * wv4.x + xv.y * wv4.y + xv.z * wv4.z + xv.w * wv4.w;
    }
  }
#pragma unroll
  for (int e = 0; e < NE; e++) {
#pragma unroll
    for (int off = 32; off > 0; off >>= 1) acc[e] += __shfl_xor(acc[e], off);
  }
  if (lane == 0) {
    float m = acc[0];
#pragma unroll
    for (int e = 1; e < NE; e++) m = fmaxf(m, acc[e]);
    float p[NE];
    float s = 0.f;
#pragma unroll
    for (int e = 0; e < NE; e++) { p[e] = expf(acc[e] - m); s += p[e]; }
    float inv = 1.f / s;
#pragma unroll
    for (int e = 0; e < NE; e++) p[e] *= inv;
    int i1 = 0;
#pragma unroll
    for (int e = 1; e < NE; e++) if (p[e] > p[i1]) i1 = e;
    int i2 = (i1 == 0) ? 1 : 0;
#pragma unroll
    for (int e = 0; e < NE; e++) if (e != i1 && p[e] > p[i2]) i2 = e;
    float denom = p[i1] + p[i2] + 1e-8f;
    topidx[token] = (unsigned char)(i1 | (i2 << 4));
    pslot[2 * token]     = p[i1] / denom;
    pslot[2 * token + 1] = p[i2] / denom;
#pragma unroll
    for (int e = 0; e < NE; e++) atomicAdd(&sp[e], p[e]);
  }
  __syncthreads();
  if (threadIdx.x < NE) partials[blockIdx.x * NE + threadIdx.x] = sp[threadIdx.x];
}

// ---------------- scatter: wave-aggregated position assignment ----------------
__global__ void scatter_kernel(const unsigned char* __restrict__ topidx,
                               int* __restrict__ counts, int* __restrict__ lists) {
  int token = blockIdx.x * blockDim.x + threadIdx.x;
  int lane = threadIdx.x & 63;
  unsigned char packed = topidx[token];
#pragma unroll
  for (int c = 0; c < 2; c++) {
    int myexp = (c == 0) ? (packed & 15) : (packed >> 4);
    int slot = 2 * token + c;
#pragma unroll
    for (int e = 0; e < NE; e++) {
      unsigned long long mask = __ballot(myexp == e);
      int cnt = __popcll(mask);
      if (cnt) {
        int base = 0;
        if (lane == 0) base = atomicAdd(&counts[e], cnt);
        base = __shfl(base, 0);
        if (myexp == e) {
          int mypos = base + __popcll(mask & ((1ull << lane) - 1ull));
          lists[e * N_TOK + mypos] = slot;
        }
      }
    }
  }
}

// ---------------- tile map + prefix (single thread, trivial) ----------------
__global__ void tilemap_kernel(const int* __restrict__ counts, int* __restrict__ prefix,
                               int2* __restrict__ tilemap) {
  if (threadIdx.x != 0) return;
  int off = 0, tix = 0;
  for (int e = 0; e < NE; e++) {
    prefix[e] = off;
    int c = counts[e];
    int ntile = (c + 255) >> 8;
    for (int m = 0; m < ntile; m++) { tilemap[tix].x = e; tilemap[tix].y = m; tix++; }
    off += c;
  }
  prefix[NE] = off;
  while (tix < 64) { tilemap[tix].x = -1; tilemap[tix].y = 0; tix++; }
}

// ---------------- aux loss ----------------
__global__ void aux_kernel(const float* __restrict__ partials, int nblk,
                           float* __restrict__ aux_out) {
  __shared__ float sp[NE];
  if (threadIdx.x < NE) sp[threadIdx.x] = 0.f;
  __syncthreads();
  float s = 0.f;
  for (int i = threadIdx.x; i < nblk * NE; i += 256) s += partials[i];
  atomicAdd(&sp[threadIdx.x & 7], s);
  __syncthreads();
  if (threadIdx.x == 0) {
    float a = 0.f;
#pragma unroll
    for (int e = 0; e < NE; e++) {
      float tpe = sp[e] * (1.0f / N_TOK);
      float d = tpe - 1.0f / NE;
      a += d * d;
    }
    aux_out[0] = 0.01f * (a * (1.0f / NE));
  }
}

// ---------------- 256x256 8-wave 4-phase grouped GEMM ----------------
// C = gather(A) * B[e]^T.  BK=64, LDS half-tiles 128x64 bf16 in 4 rotating slots
// per operand, XOR-swizzled (pre-swizzled global source + swizzled ds_read).
template <int KDIM, int NDIM, bool IS_GEMM1>
__global__ __launch_bounds__(512, 2) void moe_gemm256(
    const unsigned short* __restrict__ Aglob,
    const unsigned short* __restrict__ Bglob,
    const int* __restrict__ prefix,
    const int2* __restrict__ tilemap,
    const int* __restrict__ lists,
    const float* __restrict__ pslot,
    unsigned short* __restrict__ hb,
    float* __restrict__ o2) {
  int2 tm = tilemap[blockIdx.y];
  if (tm.x < 0) return;
  int e = tm.x, mt = tm.y, nt = blockIdx.x;
  int base = prefix[e];
  int cnt  = prefix[e + 1] - base;
  if (mt * 256 >= cnt) return;
  const int* list = lists + e * N_TOK;
  const unsigned short* B = Bglob + (size_t)e * NDIM * KDIM;

  __shared__ unsigned short As[4 * 8192];  // 4 half-slots x (128x64) bf16
  __shared__ unsigned short Bs[4 * 8192];

  int tid = threadIdx.x, wid = tid >> 6, lane = tid & 63;
  int wr = wid >> 2, wc = wid & 3;  // 2 x 4 waves; per-wave out 128x64

  // ---- staging source pointers (pre-swizzled column) ----
  int swzcol = (((lane & 7) ^ (lane >> 3)) << 3);  // elements
  const unsigned short* aptr[2][2];
  const unsigned short* bptr[2][2];
#pragma unroll
  for (int i = 0; i < 2; i++)
#pragma unroll
    for (int c = 0; c < 2; c++) {
      int r = (wid * 2 + c) * 8 + (lane >> 3);  // 0..127 within half
      int p = mt * 256 + i * 128 + r;
      int pc = p < cnt ? p : cnt - 1;
      int arow = IS_GEMM1 ? (list[pc] >> 1) : (base + pc);
      aptr[i][c] = Aglob + (size_t)arow * KDIM + swzcol;
      bptr[i][c] = B + (size_t)(nt * 256 + i * 128 + r) * KDIM + swzcol;
    }

#define STAGE_A(slot, half, kt) do { \
    __builtin_amdgcn_global_load_lds((const void*)(aptr[half][0] + (size_t)(kt) * 64), \
        (void*)(As + (slot) * 8192 + (wid * 2 + 0) * 512), 16, 0, 0); \
    __builtin_amdgcn_global_load_lds((const void*)(aptr[half][1] + (size_t)(kt) * 64), \
        (void*)(As + (slot) * 8192 + (wid * 2 + 1) * 512), 16, 0, 0); \
  } while (0)
#define STAGE_B(slot, half, kt) do { \
    __builtin_amdgcn_global_load_lds((const void*)(bptr[half][0] + (size_t)(kt) * 64), \
        (void*)(Bs + (slot) * 8192 + (wid * 2 + 0) * 512), 16, 0, 0); \
    __builtin_amdgcn_global_load_lds((const void*)(bptr[half][1] + (size_t)(kt) * 64), \
        (void*)(Bs + (slot) * 8192 + (wid * 2 + 1) * 512), 16, 0, 0); \
  } while (0)

  f32x4 acc[8][4];
#pragma unroll
  for (int m = 0; m < 8; m++)
#pragma unroll
    for (int n = 0; n < 4; n++) acc[m][n] = (f32x4){0.f, 0.f, 0.f, 0.f};

  const int T = KDIM / 64;

  // prologue: tile0 (4 halves) + A0(tile1); wait until tile0 landed (2 newest allowed out)
  STAGE_A(0, 0, 0);
  STAGE_A(1, 1, 0);
  STAGE_B(0, 0, 0);
  STAGE_B(1, 1, 0);
  STAGE_A(2, 0, (T > 1 ? 1 : 0));
  WAITV2();
  BAR();

  for (int t = 0; t < T; ++t) {
    int sa = (2 * t + wr) & 3;
    int sb = (2 * t + (wc >> 1)) & 3;
    const char* Ab = (const char*)As + sa * 16384;
    const char* Bb = (const char*)Bs + sb * 16384;
    int kt1 = (t + 1 < T) ? t + 1 : T - 1;
    int kt2 = (t + 2 < T) ? t + 2 : T - 1;

    short8 aF[4][2], bF[4][2];
    // ---- P1: read a_mh0 (8) + b_nh0 (4); stage A1(t+1); MFMA mh0 x nh0
#pragma unroll
    for (int mi = 0; mi < 4; mi++) {
      int row = mi * 16 + (lane & 15);
      int sw = (row & 7) << 4;
      int cb = (lane >> 4) * 16;
      aF[mi][0] = *(const short8*)(Ab + row * 128 + (cb ^ sw));
      aF[mi][1] = *(const short8*)(Ab + row * 128 + ((cb + 64) ^ sw));
    }
#pragma unroll
    for (int n = 0; n < 2; n++) {
      int row = (wc & 1) * 64 + n * 16 + (lane & 15);
      int sw = (row & 7) << 4;
      int cb = (lane >> 4) * 16;
      bF[n][0] = *(const short8*)(Bb + row * 128 + (cb ^ sw));
      bF[n][1] = *(const short8*)(Bb + row * 128 + ((cb + 64) ^ sw));
    }
    STAGE_A(((2 * t + 3) & 3), 1, kt1);
    BAR();
    __builtin_amdgcn_s_setprio(1);
#pragma unroll
    for (int mi = 0; mi < 4; mi++)
#pragma unroll
      for (int n = 0; n < 2; n++)
#pragma unroll
        for (int ks = 0; ks < 2; ks++)
          acc[mi][n] = __builtin_amdgcn_mfma_f32_16x16x32_bf16(aF[mi][ks], bF[n][ks], acc[mi][n], 0, 0, 0);
    __builtin_amdgcn_s_setprio(0);
    BAR();

    // ---- P2: read b_nh1 (4); stage B0(t+1); MFMA mh0 x nh1
#pragma unroll
    for (int n = 0; n < 2; n++) {
      int row = (wc & 1) * 64 + (n + 2) * 16 + (lane & 15);
      int sw = (row & 7) << 4;
      int cb = (lane >> 4) * 16;
      bF[n + 2][0] = *(const short8*)(Bb + row * 128 + (cb ^ sw));
      bF[n + 2][1] = *(const short8*)(Bb + row * 128 + ((cb + 64) ^ sw));
    }
    STAGE_B(((2 * t + 2) & 3), 0, kt1);
    BAR();
    __builtin_amdgcn_s_setprio(1);
#pragma unroll
    for (int mi = 0; mi < 4; mi++)
#pragma unroll
      for (int n = 0; n < 2; n++)
#pragma unroll
        for (int ks = 0; ks < 2; ks++)
          acc[mi][n + 2] = __builtin_amdgcn_mfma_f32_16x16x32_bf16(aF[mi][ks], bF[n + 2][ks], acc[mi][n + 2], 0, 0, 0);
    __builtin_amdgcn_s_setprio(0);
    BAR();

    // ---- P3: read a_mh1 (8, overwrite aF); stage B1(t+1); MFMA mh1 x nh1
#pragma unroll
    for (int mi = 0; mi < 4; mi++) {
      int row = (mi + 4) * 16 + (lane & 15);
      int sw = (row & 7) << 4;
      int cb = (lane >> 4) * 16;
      aF[mi][0] = *(const short8*)(Ab + row * 128 + (cb ^ sw));
      aF[mi][1] = *(const short8*)(Ab + row * 128 + ((cb + 64) ^ sw));
    }
    STAGE_B(((2 * t + 3) & 3), 1, kt1);
    BAR();
    __builtin_amdgcn_s_setprio(1);
#pragma unroll
    for (int mi = 0; mi < 4; mi++)
#pragma unroll
      for (int n = 0; n < 2; n++)
#pragma unroll
        for (int ks = 0; ks < 2; ks++)
          acc[mi + 4][n + 2] = __builtin_amdgcn_mfma_f32_16x16x32_bf16(aF[mi][ks], bF[n + 2][ks], acc[mi + 4][n + 2], 0, 0, 0);
    __builtin_amdgcn_s_setprio(0);
    BAR();

    // ---- P4: stage A0(t+2) (slot of current tile's A0 - reads done); MFMA mh1 x nh0; counted wait
    STAGE_A(((2 * t) & 3), 0, kt2);
    BAR();
    __builtin_amdgcn_s_setprio(1);
#pragma unroll
    for (int mi = 0; mi < 4; mi++)
#pragma unroll
      for (int n = 0; n < 2; n++)
#pragma unroll
        for (int ks = 0; ks < 2; ks++)
          acc[mi + 4][n] = __builtin_amdgcn_mfma_f32_16x16x32_bf16(aF[mi][ks], bF[n][ks], acc[mi + 4][n], 0, 0, 0);
    __builtin_amdgcn_s_setprio(0);
    WAITV2();
    BAR();
  }
#undef STAGE_A
#undef STAGE_B

  // ---- epilogue: C/D layout col = lane&15, row = (lane>>4)*4 + reg ----
  int colpart = nt * 256 + wc * 64 + (lane & 15);
#pragma unroll
  for (int m = 0; m < 8; m++) {
#pragma unroll
    for (int rr = 0; rr < 4; rr++) {
      int p = mt * 256 + wr * 128 + m * 16 + (lane >> 4) * 4 + rr;
      if (p < cnt) {
        if (IS_GEMM1) {
          size_t rowbase = (size_t)(base + p) * FH + colpart;
#pragma unroll
          for (int n = 0; n < 4; n++) {
            float v = acc[m][n][rr];
            float g = 0.5f * v * (1.f + erff(v * 0.70710678118654752f));
            hb[rowbase + n * 16] = f2bf(g);
          }
        } else {
          int slot = list[p];
          float sc = pslot[slot];
          size_t rowbase = (size_t)slot * DM + colpart;
#pragma unroll
          for (int n = 0; n < 4; n++) o2[rowbase + n * 16] = sc * acc[m][n][rr];
        }
      }
    }
  }
}

// ---------------- combine: out[token] = o2[2t] + o2[2t+1] ----------------
__global__ void combine_kernel(const float* __restrict__ o2, float* __restrict__ out) {
  int idx = blockIdx.x * blockDim.x + threadIdx.x;  // over N_TOK*DM/4
  int token = idx >> 8;                             // DM/4 = 256
  int d4 = idx & 255;
  float4 a = ((const float4*)(o2 + (size_t)(2 * token) * DM))[d4];
  float4 b = ((const float4*)(o2 + (size_t)(2 * token + 1) * DM))[d4];
  float4 s = {a.x + b.x, a.y + b.y, a.z + b.z, a.w + b.w};
  ((float4*)(out + (size_t)token * DM))[d4] = s;
}

extern "C" void kernel_launch(void* const* d_in, const int* in_sizes, int n_in,
                              void* d_out, int out_size, void* d_ws, size_t ws_size,
                              hipStream_t stream) {
  const float* x  = (const float*)d_in[0];
  const float* Wr = (const float*)d_in[1];
  const float* W1 = (const float*)d_in[2];
  const float* W2 = (const float*)d_in[3];
  float* out = (float*)d_out;

  char* ws = (char*)d_ws;
  int*   counts   = (int*)(ws + 0);                  // 32 B
  int*   prefix   = (int*)(ws + 64);                 // 64 B
  unsigned char* topidx = (unsigned char*)(ws + 128);  // 4096 B
  int2*  tilemap  = (int2*)(ws + 4352);              // 512 B
  float* pslot    = (float*)(ws + 8192);             // 32 KB
  float* partials = (float*)(ws + 40960);            // 32 KB
  int*   lists    = (int*)(ws + 73728);              // 128 KB -> ends 204800
  unsigned short* xb  = (unsigned short*)(ws + 204800);                      // 8 MiB
  unsigned short* w1b = (unsigned short*)(ws + 204800 + 8388608);            // 64 MiB
  unsigned short* w2b = (unsigned short*)(ws + 204800 + 8388608 + 67108864);         // 64 MiB
  unsigned short* hb  = (unsigned short*)(ws + 204800 + 8388608 + 2ull * 67108864);  // 64 MiB
  float*          o2  = (float*)(ws + 204800 + 8388608 + 3ull * 67108864);           // 32 MiB
  (void)in_sizes; (void)n_in; (void)ws_size;

  hipMemsetAsync(counts, 0, 32, stream);

  cvt_kernel<<<2048, 256, 0, stream>>>(x,  xb,  N_TOK * DM / 4);
  cvt_kernel<<<2048, 256, 0, stream>>>(W1, w1b, NE * FH * DM / 4);
  cvt_kernel<<<2048, 256, 0, stream>>>(W2, w2b, NE * DM * FH / 4);

  router_kernel<<<N_TOK / 4, 256, 0, stream>>>(x, Wr, partials, topidx, pslot);
  scatter_kernel<<<N_TOK / 256, 256, 0, stream>>>(topidx, counts, lists);
  tilemap_kernel<<<1, 64, 0, stream>>>(counts, prefix, tilemap);
  aux_kernel<<<1, 256, 0, stream>>>(partials, N_TOK / 4, out + (size_t)N_TOK * DM);

  // GEMM1: N=FH(4096), K=DM(1024); writes hb compact (gelu, bf16)
  moe_gemm256<DM, FH, true><<<dim3(FH / 256, 40), 512, 0, stream>>>(
      xb, w1b, prefix, tilemap, lists, pslot, hb, nullptr);
  // GEMM2: N=DM(1024), K=FH(4096); reads hb contiguous, writes o2 slot-major
  moe_gemm256<FH, DM, false><<<dim3(DM / 256, 40), 512, 0, stream>>>(
      hb, w2b, prefix, tilemap, lists, pslot, nullptr, o2);

  combine_kernel<<<N_TOK * DM / 4 / 256, 256, 0, stream>>>(o2, out);
}